// Round 4
// baseline (557.444 us; speedup 1.0000x reference)
//
#include <hip/hip_runtime.h>

// NeRF MLP, register-resident chain, 2 independent point-tiles per wave.
// Transposed MFMA: D = A(W^T) * B(act^T), 16x16x32 f16.
//   A-frag: m=lane&15 (out feat), k=quad*8+j  (weights, pre-packed)
//   B-frag: n=lane&15 (point),   k=quad*8+j  (activations)
//   D     : col=lane&15 (point), row=quad*4+i (out feat)
// Hidden-feature ordering permuted at pack time so D's registers (relu+cvt)
// ARE the next layer's B-fragment. Zero LDS. Two tiles interleaved
// stage-major so chain A's pack overlaps chain B's MFMA latency.

typedef _Float16 half8  __attribute__((ext_vector_type(8)));
typedef __fp16   pk16x2 __attribute__((ext_vector_type(2)));  // cvt_pkrtz return type
typedef float    floatx4 __attribute__((ext_vector_type(4)));

#define NPTS   2097152
#define NCHUNK (NPTS / 128)  // 128 pts per block-iter (4 waves x 2 tiles x 16)

// ---------- weight pre-pack: 36 fragments x 64 lanes x 8 halfs -> d_ws ----
__global__ void prep_weights(const float* __restrict__ ws0, const float* __restrict__ ws1,
                             const float* __restrict__ ws2, const float* __restrict__ wc0,
                             const float* __restrict__ wc1, const float* __restrict__ wc2,
                             const float* __restrict__ wc3, _Float16* __restrict__ wpack) {
    int t = blockIdx.x * blockDim.x + threadIdx.x;
    if (t >= 36 * 64) return;
    int fid = t >> 6, lane = t & 63, l16 = lane & 15, q = lane >> 4;
#pragma unroll
    for (int j = 0; j < 8; ++j) {
        float v = 0.f;
        if (fid < 4) {                       // s0: natural input dims, mt=fid
            v = ws0[(q * 8 + j) * 64 + fid * 16 + l16];
        } else if (fid < 12) {               // s1: mt=(fid-4)>>1, c=(fid-4)&1
            int mt = (fid - 4) >> 1, c = (fid - 4) & 1;
            int p = (2 * c + (j >> 2)) * 16 + q * 4 + (j & 3);
            v = ws1[p * 64 + mt * 16 + l16];
        } else if (fid < 14) {               // s2: c=fid-12, 16 outs
            int c = fid - 12;
            int p = (2 * c + (j >> 2)) * 16 + q * 4 + (j & 3);
            v = ws2[p * 16 + l16];
        } else if (fid < 18) {               // c0: mt=fid-14; views j<4, geo j>=4
            int mt = fid - 14;
            if (j < 4) v = wc0[(q * 4 + j) * 64 + mt * 16 + l16];
            else {
                int g = q * 4 + (j - 4);     // geo feat index (0 => sigma slot, pad)
                v = (g == 0) ? 0.f : wc0[(15 + g) * 64 + mt * 16 + l16];
            }
        } else if (fid < 26) {               // c1
            int mt = (fid - 18) >> 1, c = (fid - 18) & 1;
            int p = (2 * c + (j >> 2)) * 16 + q * 4 + (j & 3);
            v = wc1[p * 64 + mt * 16 + l16];
        } else if (fid < 34) {               // c2
            int mt = (fid - 26) >> 1, c = (fid - 26) & 1;
            int p = (2 * c + (j >> 2)) * 16 + q * 4 + (j & 3);
            v = wc2[p * 64 + mt * 16 + l16];
        } else {                             // c3: c=fid-34, 3 outs (pad cols >=3)
            int c = fid - 34;
            int p = (2 * c + (j >> 2)) * 16 + q * 4 + (j & 3);
            v = (l16 < 3) ? wc3[p * 3 + l16] : 0.f;
        }
        wpack[t * 8 + j] = (_Float16)v;
    }
}

__device__ __forceinline__ half8 packrelu(floatx4 a, floatx4 b) {
    half8 r; pk16x2 t;
    t = __builtin_amdgcn_cvt_pkrtz(fmaxf(a[0], 0.f), fmaxf(a[1], 0.f)); r[0] = t[0]; r[1] = t[1];
    t = __builtin_amdgcn_cvt_pkrtz(fmaxf(a[2], 0.f), fmaxf(a[3], 0.f)); r[2] = t[0]; r[3] = t[1];
    t = __builtin_amdgcn_cvt_pkrtz(fmaxf(b[0], 0.f), fmaxf(b[1], 0.f)); r[4] = t[0]; r[5] = t[1];
    t = __builtin_amdgcn_cvt_pkrtz(fmaxf(b[2], 0.f), fmaxf(b[3], 0.f)); r[6] = t[0]; r[7] = t[1];
    return r;
}

__global__ __launch_bounds__(256, 2)
void nerf_fused(const float* __restrict__ x, const _Float16* __restrict__ wpack,
                float* __restrict__ out) {
    const int lane = threadIdx.x & 63;
    const int w    = threadIdx.x >> 6;
    const int l16  = lane & 15;
    const int q    = lane >> 4;

    half8 W[36];
    const half8* wp = (const half8*)wpack;
#pragma unroll
    for (int f = 0; f < 36; ++f) W[f] = wp[f * 64 + lane];

    const floatx4 vz = {0.f, 0.f, 0.f, 0.f};
    const float4* xb = (const float4*)x;

    int chunk = blockIdx.x;
    float4 vA[2], vB[2], vC[2];
#pragma unroll
    for (int u = 0; u < 2; ++u) {
        size_t base = (size_t)(chunk * 128 + w * 32 + u * 16 + l16) * 12;
        vA[u] = xb[base + q * 2]; vB[u] = xb[base + q * 2 + 1]; vC[u] = xb[base + 8 + q];
    }

    while (chunk < NCHUNK) {
        int next = chunk + gridDim.x;
        int pf = next < NCHUNK ? next : chunk;

        // ---- s0: B directly from x (dims q*8..q*8+7), K=32 ----
        half8 b0[2], b1[2];
        floatx4 acc[2][4], a2[2][4];
#pragma unroll
        for (int u = 0; u < 2; ++u) {
            pk16x2 t;
            t = __builtin_amdgcn_cvt_pkrtz(vA[u].x, vA[u].y); b0[u][0] = t[0]; b0[u][1] = t[1];
            t = __builtin_amdgcn_cvt_pkrtz(vA[u].z, vA[u].w); b0[u][2] = t[0]; b0[u][3] = t[1];
            t = __builtin_amdgcn_cvt_pkrtz(vB[u].x, vB[u].y); b0[u][4] = t[0]; b0[u][5] = t[1];
            t = __builtin_amdgcn_cvt_pkrtz(vB[u].z, vB[u].w); b0[u][6] = t[0]; b0[u][7] = t[1];
        }
#pragma unroll
        for (int mt = 0; mt < 4; ++mt)
#pragma unroll
            for (int u = 0; u < 2; ++u)
                acc[u][mt] = __builtin_amdgcn_mfma_f32_16x16x32_f16(W[mt], b0[u], vz, 0, 0, 0);

        // ---- s1 ----
#pragma unroll
        for (int u = 0; u < 2; ++u) {
            b0[u] = packrelu(acc[u][0], acc[u][1]);
            b1[u] = packrelu(acc[u][2], acc[u][3]);
        }
#pragma unroll
        for (int mt = 0; mt < 4; ++mt)
#pragma unroll
            for (int u = 0; u < 2; ++u) {
                a2[u][mt] = __builtin_amdgcn_mfma_f32_16x16x32_f16(W[4 + mt * 2], b0[u], vz,        0, 0, 0);
                a2[u][mt] = __builtin_amdgcn_mfma_f32_16x16x32_f16(W[5 + mt * 2], b1[u], a2[u][mt], 0, 0, 0);
            }

        // ---- s2 (no relu): sigma = feat0, geo = feats 1..15 ----
#pragma unroll
        for (int u = 0; u < 2; ++u) {
            b0[u] = packrelu(a2[u][0], a2[u][1]);
            b1[u] = packrelu(a2[u][2], a2[u][3]);
        }
        floatx4 accS[2];
        float sigma[2];
#pragma unroll
        for (int u = 0; u < 2; ++u) {
            accS[u] = __builtin_amdgcn_mfma_f32_16x16x32_f16(W[12], b0[u], vz,      0, 0, 0);
            accS[u] = __builtin_amdgcn_mfma_f32_16x16x32_f16(W[13], b1[u], accS[u], 0, 0, 0);
        }

        // ---- c0: B = {views q*4..q*4+3 from vC, geo from accS}, K=32 ----
#pragma unroll
        for (int u = 0; u < 2; ++u) {
            sigma[u] = accS[u][0];
            pk16x2 t;
            t = __builtin_amdgcn_cvt_pkrtz(vC[u].x, vC[u].y); b0[u][0] = t[0]; b0[u][1] = t[1];
            t = __builtin_amdgcn_cvt_pkrtz(vC[u].z, vC[u].w); b0[u][2] = t[0]; b0[u][3] = t[1];
            float g0 = (q == 0) ? 0.f : accS[u][0];
            t = __builtin_amdgcn_cvt_pkrtz(g0, accS[u][1]);         b0[u][4] = t[0]; b0[u][5] = t[1];
            t = __builtin_amdgcn_cvt_pkrtz(accS[u][2], accS[u][3]); b0[u][6] = t[0]; b0[u][7] = t[1];
        }
#pragma unroll
        for (int mt = 0; mt < 4; ++mt)
#pragma unroll
            for (int u = 0; u < 2; ++u)
                acc[u][mt] = __builtin_amdgcn_mfma_f32_16x16x32_f16(W[14 + mt], b0[u], vz, 0, 0, 0);

        // ---- x regs dead: issue next iteration's loads (latency covered by c1..c3) ----
#pragma unroll
        for (int u = 0; u < 2; ++u) {
            size_t nbase = (size_t)(pf * 128 + w * 32 + u * 16 + l16) * 12;
            vA[u] = xb[nbase + q * 2]; vB[u] = xb[nbase + q * 2 + 1]; vC[u] = xb[nbase + 8 + q];
        }

        // ---- c1 ----
#pragma unroll
        for (int u = 0; u < 2; ++u) {
            b0[u] = packrelu(acc[u][0], acc[u][1]);
            b1[u] = packrelu(acc[u][2], acc[u][3]);
        }
#pragma unroll
        for (int mt = 0; mt < 4; ++mt)
#pragma unroll
            for (int u = 0; u < 2; ++u) {
                a2[u][mt] = __builtin_amdgcn_mfma_f32_16x16x32_f16(W[18 + mt * 2], b0[u], vz,        0, 0, 0);
                a2[u][mt] = __builtin_amdgcn_mfma_f32_16x16x32_f16(W[19 + mt * 2], b1[u], a2[u][mt], 0, 0, 0);
            }

        // ---- c2 ----
#pragma unroll
        for (int u = 0; u < 2; ++u) {
            b0[u] = packrelu(a2[u][0], a2[u][1]);
            b1[u] = packrelu(a2[u][2], a2[u][3]);
        }
#pragma unroll
        for (int mt = 0; mt < 4; ++mt)
#pragma unroll
            for (int u = 0; u < 2; ++u) {
                acc[u][mt] = __builtin_amdgcn_mfma_f32_16x16x32_f16(W[26 + mt * 2], b0[u], vz,         0, 0, 0);
                acc[u][mt] = __builtin_amdgcn_mfma_f32_16x16x32_f16(W[27 + mt * 2], b1[u], acc[u][mt], 0, 0, 0);
            }

        // ---- c3 (no relu, 3 outs) ----
#pragma unroll
        for (int u = 0; u < 2; ++u) {
            b0[u] = packrelu(acc[u][0], acc[u][1]);
            b1[u] = packrelu(acc[u][2], acc[u][3]);
        }
        floatx4 accC[2];
#pragma unroll
        for (int u = 0; u < 2; ++u) {
            accC[u] = __builtin_amdgcn_mfma_f32_16x16x32_f16(W[34], b0[u], vz,      0, 0, 0);
            accC[u] = __builtin_amdgcn_mfma_f32_16x16x32_f16(W[35], b1[u], accC[u], 0, 0, 0);
        }

        // ---- store: quad-0 lanes hold color rows 0..2 + sigma for pt=l16 ----
        if (lane < 16) {
#pragma unroll
            for (int u = 0; u < 2; ++u) {
                float4 o;
                o.x = accC[u][0]; o.y = accC[u][1]; o.z = accC[u][2]; o.w = sigma[u];
                ((float4*)out)[(size_t)chunk * 128 + w * 32 + u * 16 + lane] = o;
            }
        }

        chunk = next;
    }
}

extern "C" void kernel_launch(void* const* d_in, const int* in_sizes, int n_in,
                              void* d_out, int out_size, void* d_ws, size_t ws_size,
                              hipStream_t stream) {
    _Float16* wpack = (_Float16*)d_ws;  // 36*64*8 halfs = 36 KB
    prep_weights<<<9, 256, 0, stream>>>(
        (const float*)d_in[1], (const float*)d_in[2], (const float*)d_in[3],
        (const float*)d_in[4], (const float*)d_in[5], (const float*)d_in[6],
        (const float*)d_in[7], wpack);
    nerf_fused<<<1024, 256, 0, stream>>>((const float*)d_in[0], wpack, (float*)d_out);
}